// Round 6
// baseline (971.365 us; speedup 1.0000x reference)
//
#include <hip/hip_runtime.h>

// SSIM3D loss, fused separable 11^3 Gaussian conv of 5 fields + SSIM map + mean.
// Round 5 (resubmit): (a) async global_load_lds staging into linear
// double-buffered LDS (no prefetch VGPRs, no ds_write staging), OOB lanes ->
// zero-quad in d_ws; (b) D-conv as 11 rotating accumulators with switch(s%11)
// static phases (no ring shift moves); (c) b128 W-conv 4-wide + H-conv 2-wide.

#define DD 128
#define HH 256
#define WW 256
#define TH 32
#define TW 16
#define DC 32
#define SLICES (DC + 10)      // 42
#define KS 11
#define XH 42                 // staged rows
#define XSTR 32               // floats; linear: lane quad = tid*16B (DMA constraint)
#define XN (XH * XSTR)        // 1344 floats per field per buffer
#define WBAS 17               // wbA row stride (float4)
#define WBBS 20               // wbB row stride (floats), 16B-aligned quads
#define NTH 512
#define PLANE 65536
#define C1F 1.0e-4f
#define C2F 9.0e-4f
#define NVOX (2.0 * 128.0 * 256.0 * 256.0)

// init: zero accumulator + zero-quad, extract separable g[11] from 11^3 window
__global__ void ssim_init_kernel(const float* __restrict__ win,
                                 double* __restrict__ acc,
                                 float* __restrict__ g,
                                 float* __restrict__ zq) {
    int i = threadIdx.x;
    if (i == 0) acc[0] = 0.0;
    if (i < 4) zq[i] = 0.f;
    if (i < KS) {
        float s = 0.f;
        #pragma unroll 1
        for (int j = 0; j < KS * KS; ++j) s += win[i * KS * KS + j];
        g[i] = s;
    }
}

// one D-phase: add slice contribution to all 11 pending outputs (static G idx),
// emit + reset the completing slot (p+1)%11.
template<int P>
__device__ __forceinline__ void dstep(float (&A)[5][KS], const float (&G)[KS],
                                      const float4 S, const float s4v,
                                      const bool doEmit, double& lsum) {
    const float v0 = S.x, v1 = S.y, v2 = S.z, v3 = S.w, v4 = s4v;
    #pragma unroll
    for (int j = 0; j < KS; ++j) {
        const int gi = (P - j + KS) % KS;        // static after unroll
        const float g = G[gi];
        A[0][j] = fmaf(g, v0, A[0][j]);
        A[1][j] = fmaf(g, v1, A[1][j]);
        A[2][j] = fmaf(g, v2, A[2][j]);
        A[3][j] = fmaf(g, v3, A[3][j]);
        A[4][j] = fmaf(g, v4, A[4][j]);
    }
    const int je = (P + 1) % KS;
    if (doEmit) {
        const float m1 = A[0][je], m2 = A[1][je];
        const float exx = A[2][je], eyy = A[3][je], exy = A[4][je];
        const float mu11 = m1 * m1, mu22 = m2 * m2, mu12 = m1 * m2;
        const float sg1 = exx - mu11, sg2 = eyy - mu22, sg12 = exy - mu12;
        const float num = (2.f * mu12 + C1F) * (2.f * sg12 + C2F);
        const float den = (mu11 + mu22 + C1F) * (sg1 + sg2 + C2F);
        lsum += (double)(num / den);
    }
    A[0][je] = 0.f; A[1][je] = 0.f; A[2][je] = 0.f; A[3][je] = 0.f; A[4][je] = 0.f;
}

__global__ __launch_bounds__(NTH, 4)
void ssim_main_kernel(const float* __restrict__ img1,
                      const float* __restrict__ img2,
                      const float* __restrict__ gcoef,
                      const float* __restrict__ zbuf,
                      double* __restrict__ acc) {
    __shared__ __align__(16) float xt[2][XN];
    __shared__ __align__(16) float yt[2][XN];
    __shared__ float4 wbA[XH * WBAS];             // fields x, y, xx, yy
    __shared__ __align__(16) float wbB[XH * WBBS]; // field xy
    __shared__ float4 xfA[TH * TW];
    __shared__ float  xfB[TH * TW];
    __shared__ double red[NTH / 64];

    const int tid = threadIdx.x;
    const int tx = tid & 15;
    const int ty = tid >> 4;
    const int w0 = blockIdx.x * TW;
    const int h0 = blockIdx.y * TH;
    const int b  = blockIdx.z >> 2;
    const int d0 = (blockIdx.z & 3) * DC;

    const float* base1 = img1 + (size_t)b * (DD * PLANE);
    const float* base2 = img2 + (size_t)b * (DD * PLANE);

    // staging geometry: 336 quad-tasks = 42 rows x 8 float4 cols, LDS linear in tid
    const int sr = tid >> 3;
    const int sq = tid & 7;
    const int gh = h0 - 5 + sr;
    const int gw = w0 - 8 + (sq << 2);
    const bool sOk = (tid < 336) && ((unsigned)gh < HH) && ((unsigned)gw < WW);
    const int gOfs = sOk ? (gh * WW + gw) : 0;
    const float* pB1 = base1 + gOfs;              // depth-0 plane, per-lane
    const float* pB2 = base2 + gOfs;
    const int ldsoff = (tid >> 6) << 8;           // wave-uniform base (floats)

    float G[KS];
    #pragma unroll
    for (int i = 0; i < KS; ++i) G[i] = gcoef[i];

    float dacc[5][KS] = {};                       // static-indexed only

    // prologue: issue slice 0 (depth d0-5) into buffer 0
    {
        const int dIn = d0 - 5;
        const bool dOK = ((unsigned)dIn < DD);
        if (tid < 336) {
            const float* g1 = (sOk && dOK) ? (pB1 + (size_t)dIn * PLANE) : zbuf;
            const float* g2 = (sOk && dOK) ? (pB2 + (size_t)dIn * PLANE) : zbuf;
            __builtin_amdgcn_global_load_lds(
                (const __attribute__((address_space(1))) void*)g1,
                (__attribute__((address_space(3))) void*)&xt[0][ldsoff], 16, 0, 0);
            __builtin_amdgcn_global_load_lds(
                (const __attribute__((address_space(1))) void*)g2,
                (__attribute__((address_space(3))) void*)&yt[0][ldsoff], 16, 0, 0);
        }
    }
    __syncthreads();   // drains vmcnt: xt[0]/yt[0] ready

    double lsum = 0.0;
    int p = 0;

    for (int s = 0; s < SLICES; ++s) {
        const int cur = s & 1, nxt = cur ^ 1;

        // 1. issue async loads for slice s+1 into the other buffer
        {
            const int dIn = d0 - 4 + s;
            const bool dOK = ((unsigned)dIn < DD) && (s < SLICES - 1);
            if (tid < 336) {
                const float* g1 = (sOk && dOK) ? (pB1 + (size_t)dIn * PLANE) : zbuf;
                const float* g2 = (sOk && dOK) ? (pB2 + (size_t)dIn * PLANE) : zbuf;
                __builtin_amdgcn_global_load_lds(
                    (const __attribute__((address_space(1))) void*)g1,
                    (__attribute__((address_space(3))) void*)&xt[nxt][ldsoff], 16, 0, 0);
                __builtin_amdgcn_global_load_lds(
                    (const __attribute__((address_space(1))) void*)g2,
                    (__attribute__((address_space(3))) void*)&yt[nxt][ldsoff], 16, 0, 0);
            }
        }

        // 2. W-conv: 168 tasks x 4 outputs, b128 reads
        if (tid < 168) {
            const int r = tid >> 2, q = tid & 3;
            const float* xp = &xt[cur][r * XSTR + (q << 2)];
            const float* yp = &yt[cur][r * XSTR + (q << 2)];
            float a0[4] = {0,0,0,0}, a1[4] = {0,0,0,0}, a2[4] = {0,0,0,0},
                  a3[4] = {0,0,0,0}, a4[4] = {0,0,0,0};
            #pragma unroll
            for (int bdx = 0; bdx < 5; ++bdx) {
                const float4 xv4 = *(const float4*)(xp + (bdx << 2));
                const float4 yv4 = *(const float4*)(yp + (bdx << 2));
                #pragma unroll
                for (int i = 0; i < 4; ++i) {
                    const int c = bdx * 4 + i;          // local staged col
                    if (c < 3 || c > 16) continue;      // taps live in [3,16]
                    const float xv = (i == 0) ? xv4.x : (i == 1) ? xv4.y : (i == 2) ? xv4.z : xv4.w;
                    const float yv = (i == 0) ? yv4.x : (i == 1) ? yv4.y : (i == 2) ? yv4.z : yv4.w;
                    #pragma unroll
                    for (int j = 0; j < 4; ++j) {
                        const int k = c - 3 - j;
                        if (k < 0 || k >= KS) continue;
                        const float t1 = G[k] * xv;
                        const float t2 = G[k] * yv;
                        a0[j] += t1;
                        a1[j] += t2;
                        a2[j] = fmaf(t1, xv, a2[j]);
                        a3[j] = fmaf(t2, yv, a3[j]);
                        a4[j] = fmaf(t1, yv, a4[j]);
                    }
                }
            }
            #pragma unroll
            for (int j = 0; j < 4; ++j)
                wbA[r * WBAS + (q << 2) + j] = make_float4(a0[j], a1[j], a2[j], a3[j]);
            *(float4*)&wbB[r * WBBS + (q << 2)] = make_float4(a4[0], a4[1], a4[2], a4[3]);
        }
        __syncthreads();   // wb ready

        // 3. H-conv 2-wide: 256 threads, rows 2m2 & 2m2+1, 12 shared taps
        if (tid < 256) {
            const int m2 = tid >> 4;
            const int cx = tid & 15;
            float b0 = 0.f, b1 = 0.f, b2 = 0.f, b3 = 0.f, b4 = 0.f;
            float c0 = 0.f, c1 = 0.f, c2 = 0.f, c3 = 0.f, c4 = 0.f;
            #pragma unroll
            for (int j = 0; j < KS + 1; ++j) {
                const float4 A = wbA[(2 * m2 + j) * WBAS + cx];
                const float  B = wbB[(2 * m2 + j) * WBBS + cx];
                if (j < KS) {
                    const float gk = G[j];
                    b0 = fmaf(gk, A.x, b0); b1 = fmaf(gk, A.y, b1);
                    b2 = fmaf(gk, A.z, b2); b3 = fmaf(gk, A.w, b3);
                    b4 = fmaf(gk, B,   b4);
                }
                if (j >= 1) {
                    const float gk = G[j - 1];
                    c0 = fmaf(gk, A.x, c0); c1 = fmaf(gk, A.y, c1);
                    c2 = fmaf(gk, A.z, c2); c3 = fmaf(gk, A.w, c3);
                    c4 = fmaf(gk, B,   c4);
                }
            }
            const int o0 = (2 * m2) * TW + cx;
            xfA[o0]      = make_float4(b0, b1, b2, b3);
            xfB[o0]      = b4;
            xfA[o0 + TW] = make_float4(c0, c1, c2, c3);
            xfB[o0 + TW] = c4;
        }
        __syncthreads();   // xf ready; vmcnt drained -> xt[nxt] ready for next iter

        // 4. D-accumulate + emit (all threads, own voxel)
        {
            const float4 S = xfA[ty * TW + tx];
            const float s4v = xfB[ty * TW + tx];
            const bool doE = (s >= 10);
            switch (p) {
                case 0:  dstep<0>(dacc, G, S, s4v, doE, lsum); break;
                case 1:  dstep<1>(dacc, G, S, s4v, doE, lsum); break;
                case 2:  dstep<2>(dacc, G, S, s4v, doE, lsum); break;
                case 3:  dstep<3>(dacc, G, S, s4v, doE, lsum); break;
                case 4:  dstep<4>(dacc, G, S, s4v, doE, lsum); break;
                case 5:  dstep<5>(dacc, G, S, s4v, doE, lsum); break;
                case 6:  dstep<6>(dacc, G, S, s4v, doE, lsum); break;
                case 7:  dstep<7>(dacc, G, S, s4v, doE, lsum); break;
                case 8:  dstep<8>(dacc, G, S, s4v, doE, lsum); break;
                case 9:  dstep<9>(dacc, G, S, s4v, doE, lsum); break;
                default: dstep<10>(dacc, G, S, s4v, doE, lsum); break;
            }
            p = (p == 10) ? 0 : p + 1;
        }
    }

    // block reduction -> one f64 atomic
    #pragma unroll
    for (int off = 32; off > 0; off >>= 1)
        lsum += __shfl_down(lsum, off, 64);
    const int lane = tid & 63, wid = tid >> 6;
    if (lane == 0) red[wid] = lsum;
    __syncthreads();
    if (tid == 0) {
        double bsum = 0.0;
        #pragma unroll
        for (int wv = 0; wv < NTH / 64; ++wv) bsum += red[wv];
        atomicAdd(acc, bsum);
    }
}

__global__ void ssim_fin_kernel(const double* __restrict__ acc,
                                float* __restrict__ out) {
    out[0] = (float)(1.0 - acc[0] / NVOX);
}

extern "C" void kernel_launch(void* const* d_in, const int* in_sizes, int n_in,
                              void* d_out, int out_size, void* d_ws, size_t ws_size,
                              hipStream_t stream) {
    const float* img1 = (const float*)d_in[0];
    const float* img2 = (const float*)d_in[1];
    const float* win  = (const float*)d_in[2];
    double* acc = (double*)d_ws;
    float*  g   = (float*)((char*)d_ws + 16);
    float*  zq  = (float*)((char*)d_ws + 64);

    hipLaunchKernelGGL(ssim_init_kernel, dim3(1), dim3(64), 0, stream, win, acc, g, zq);
    hipLaunchKernelGGL(ssim_main_kernel, dim3(WW / TW, HH / TH, 2 * (DD / DC)),
                       dim3(NTH), 0, stream, img1, img2, g, zq, acc);
    hipLaunchKernelGGL(ssim_fin_kernel, dim3(1), dim3(1), 0, stream, acc, (float*)d_out);
}

// Round 7
// 322.391 us; speedup vs baseline: 3.0130x; 3.0130x over previous
//
#include <hip/hip_runtime.h>

// SSIM3D loss, fused separable 11^3 Gaussian conv of 5 fields + SSIM map + mean.
// Round 7 = round 2 (best measured: 300us) with exactly three fixes:
//   XSTR 28->48  (48%32=16: 2-way LDS aliasing only -- free; round-1-proven)
//   WBSTR 17->16 (wb plane reads/writes contiguous-in-lane -- free; round-1-proven)
//   __launch_bounds__(512,2) (empirically (512,4) caps VGPR at 64 -> spill risk;
//   (512,2) gives a 128-reg cap while still allowing 2 blocks/CU residency)

#define DD 128
#define HH 256
#define WW 256
#define TH 32
#define TW 16
#define DC 32              // D outputs per block
#define KS 11
#define HALO 5
#define XH 42              // TH + 10
#define XW 26              // TW + 10
#define XSTR 48            // padded LDS row stride (floats); 48%32=16 -> 2-way only
#define WBSTR 16           // wb row stride (floats); lane-contiguous -> conflict-free
#define WBPL (XH * WBSTR)  // 672 floats per field plane
#define NTH 512
#define NPTS (XH * XW)     // 1092 staging points
#define PLANE 65536        // 256*256
#define C1F 1.0e-4f
#define C2F 9.0e-4f
#define NVOX (2.0 * 128.0 * 256.0 * 256.0)

// init: zero accumulator, extract separable g[11] (row sums of the 11^3 window)
__global__ void ssim_init_kernel(const float* __restrict__ win,
                                 double* __restrict__ acc,
                                 float* __restrict__ g) {
    int i = threadIdx.x;
    if (i == 0) acc[0] = 0.0;
    if (i < KS) {
        float s = 0.f;
        #pragma unroll 1
        for (int j = 0; j < KS * KS; ++j) s += win[i * KS * KS + j];
        g[i] = s;
    }
}

__global__ __launch_bounds__(NTH, 2)
void ssim_main_kernel(const float* __restrict__ img1,
                      const float* __restrict__ img2,
                      const float* __restrict__ gcoef,
                      double* __restrict__ acc) {
    __shared__ float xt[XH * XSTR];
    __shared__ float yt[XH * XSTR];
    __shared__ float wb[5 * WBPL];
    __shared__ double red[NTH / 64];

    const int tid = threadIdx.x;
    const int tx = tid & 15;
    const int ty = tid >> 4;              // 0..31
    const int w0 = blockIdx.x * TW;
    const int h0 = blockIdx.y * TH;
    const int b  = blockIdx.z >> 2;       // batch
    const int d0 = (blockIdx.z & 3) * DC; // chunk start in D

    const float* base1 = img1 + (size_t)b * (DD * PLANE);
    const float* base2 = img2 + (size_t)b * (DD * PLANE);

    // --- hoisted staging geometry: 3 segments of 512 covering 1092 points ---
    int   goff[3];   // 32-bit global in-plane offset (clamped)
    int   loff[3];   // LDS offset (floats)
    float mskf[3];   // 0 for out-of-plane halo lanes
    #pragma unroll
    for (int sg = 0; sg < 3; ++sg) {
        int p = tid + sg * NTH;
        int r = p / XW;
        int c = p - r * XW;
        int gh = h0 - HALO + r;
        int gw = w0 - HALO + c;
        bool v = (p < NPTS) && ((unsigned)gh < HH) && ((unsigned)gw < WW);
        goff[sg] = v ? (gh * WW + gw) : 0;
        mskf[sg] = v ? 1.f : 0.f;
        loff[sg] = r * XSTR + c;
    }

    float G[KS];
    #pragma unroll
    for (int i = 0; i < KS; ++i) G[i] = gcoef[i];

    float ring[5][KS];
    #pragma unroll
    for (int f = 0; f < 5; ++f)
        #pragma unroll
        for (int i = 0; i < KS; ++i) ring[f][i] = 0.f;

    // --- prefetch slice s=0 (dIn = d0-5) ---
    float pv1[3], pv2[3];
    {
        int dIn = d0 - HALO;
        if ((unsigned)dIn < DD) {
            const float* s1 = base1 + dIn * PLANE;
            const float* s2 = base2 + dIn * PLANE;
            #pragma unroll
            for (int sg = 0; sg < 3; ++sg) {
                pv1[sg] = s1[goff[sg]];
                pv2[sg] = s2[goff[sg]];
            }
        } else {
            #pragma unroll
            for (int sg = 0; sg < 3; ++sg) { pv1[sg] = 0.f; pv2[sg] = 0.f; }
        }
    }

    double lsum = 0.0;

    for (int s = 0; s < DC + 2 * HALO; ++s) {
        // shift D-ring (statically indexed)
        #pragma unroll
        for (int f = 0; f < 5; ++f)
            #pragma unroll
            for (int i = 0; i < KS - 1; ++i) ring[f][i] = ring[f][i + 1];

        // commit prefetched slice to LDS (halo lanes zeroed by mask)
        #pragma unroll
        for (int sg = 0; sg < 3; ++sg) {
            int p = tid + sg * NTH;
            if (p < NPTS) {
                xt[loff[sg]] = pv1[sg] * mskf[sg];
                yt[loff[sg]] = pv2[sg] * mskf[sg];
            }
        }
        __syncthreads();

        // issue prefetch for next slice; lands under W/H-conv
        {
            int dIn = d0 - HALO + s + 1;
            if ((s + 1 < DC + 2 * HALO) && ((unsigned)dIn < DD)) {
                const float* s1 = base1 + dIn * PLANE;
                const float* s2 = base2 + dIn * PLANE;
                #pragma unroll
                for (int sg = 0; sg < 3; ++sg) {
                    pv1[sg] = s1[goff[sg]];
                    pv2[sg] = s2[goff[sg]];
                }
            } else {
                #pragma unroll
                for (int sg = 0; sg < 3; ++sg) { pv1[sg] = 0.f; pv2[sg] = 0.f; }
            }
        }

        // W-conv segment A: rows 0..31 (all 512 threads)
        {
            const float* xrow = &xt[ty * XSTR + tx];
            const float* yrow = &yt[ty * XSTR + tx];
            float a0 = 0.f, a1 = 0.f, a2 = 0.f, a3 = 0.f, a4 = 0.f;
            #pragma unroll
            for (int k = 0; k < KS; ++k) {
                float xv = xrow[k], yv = yrow[k], gk = G[k];
                float txv = gk * xv, tyv = gk * yv;
                a0 += txv; a1 += tyv;
                a2 += txv * xv; a3 += tyv * yv; a4 += txv * yv;
            }
            int o = ty * WBSTR + tx;
            wb[o] = a0; wb[WBPL + o] = a1; wb[2 * WBPL + o] = a2;
            wb[3 * WBPL + o] = a3; wb[4 * WBPL + o] = a4;
        }
        // W-conv segment B: rows 32..41 (first 160 threads)
        if (tid < (XH * TW - NTH)) {
            int r = TH + ty;   // 32..41
            const float* xrow = &xt[r * XSTR + tx];
            const float* yrow = &yt[r * XSTR + tx];
            float a0 = 0.f, a1 = 0.f, a2 = 0.f, a3 = 0.f, a4 = 0.f;
            #pragma unroll
            for (int k = 0; k < KS; ++k) {
                float xv = xrow[k], yv = yrow[k], gk = G[k];
                float txv = gk * xv, tyv = gk * yv;
                a0 += txv; a1 += tyv;
                a2 += txv * xv; a3 += tyv * yv; a4 += txv * yv;
            }
            int o = r * WBSTR + tx;
            wb[o] = a0; wb[WBPL + o] = a1; wb[2 * WBPL + o] = a2;
            wb[3 * WBPL + o] = a3; wb[4 * WBPL + o] = a4;
        }
        __syncthreads();

        // H-conv: one output per thread
        float s0 = 0.f, s1 = 0.f, s2 = 0.f, s3 = 0.f, s4 = 0.f;
        #pragma unroll
        for (int k = 0; k < KS; ++k) {
            int o = (ty + k) * WBSTR + tx;
            float gk = G[k];
            s0 += gk * wb[o];
            s1 += gk * wb[WBPL + o];
            s2 += gk * wb[2 * WBPL + o];
            s3 += gk * wb[3 * WBPL + o];
            s4 += gk * wb[4 * WBPL + o];
        }
        ring[0][KS-1] = s0; ring[1][KS-1] = s1; ring[2][KS-1] = s2;
        ring[3][KS-1] = s3; ring[4][KS-1] = s4;

        // emit output slice d0 + s - 10
        if (s >= 2 * HALO) {
            float m1 = 0.f, m2 = 0.f, exx = 0.f, eyy = 0.f, exy = 0.f;
            #pragma unroll
            for (int i = 0; i < KS; ++i) {
                float gi = G[i];
                m1  += gi * ring[0][i];
                m2  += gi * ring[1][i];
                exx += gi * ring[2][i];
                eyy += gi * ring[3][i];
                exy += gi * ring[4][i];
            }
            float mu11 = m1 * m1, mu22 = m2 * m2, mu12 = m1 * m2;
            float sg1  = exx - mu11;
            float sg2  = eyy - mu22;
            float sg12 = exy - mu12;
            float num = (2.f * mu12 + C1F) * (2.f * sg12 + C2F);
            float den = (mu11 + mu22 + C1F) * (sg1 + sg2 + C2F);
            lsum += (double)(num / den);
        }
    }

    // block reduction -> one f64 atomic
    #pragma unroll
    for (int off = 32; off > 0; off >>= 1)
        lsum += __shfl_down(lsum, off, 64);
    int lane = tid & 63, wid = tid >> 6;
    if (lane == 0) red[wid] = lsum;
    __syncthreads();
    if (tid == 0) {
        double bsum = 0.0;
        #pragma unroll
        for (int wv = 0; wv < NTH / 64; ++wv) bsum += red[wv];
        atomicAdd(acc, bsum);
    }
}

__global__ void ssim_fin_kernel(const double* __restrict__ acc,
                                float* __restrict__ out) {
    out[0] = (float)(1.0 - acc[0] / NVOX);
}

extern "C" void kernel_launch(void* const* d_in, const int* in_sizes, int n_in,
                              void* d_out, int out_size, void* d_ws, size_t ws_size,
                              hipStream_t stream) {
    const float* img1 = (const float*)d_in[0];
    const float* img2 = (const float*)d_in[1];
    const float* win  = (const float*)d_in[2];
    double* acc = (double*)d_ws;
    float*  g   = (float*)((char*)d_ws + 16);

    hipLaunchKernelGGL(ssim_init_kernel, dim3(1), dim3(64), 0, stream, win, acc, g);
    hipLaunchKernelGGL(ssim_main_kernel, dim3(WW / TW, HH / TH, 2 * (DD / DC)),
                       dim3(NTH), 0, stream, img1, img2, g, acc);
    hipLaunchKernelGGL(ssim_fin_kernel, dim3(1), dim3(1), 0, stream, acc, (float*)d_out);
}